// Round 2
// baseline (5073.669 us; speedup 1.0000x reference)
//
#include <hip/hip_runtime.h>

// ---------------------------------------------------------------------------
// SentenceClassifier: emb -> token BiLSTM (fused input proj, persistent)
// -> folded hop attention -> sentence BiLSTM (persistent) -> linear.
// fp16 MFMA/storage for big tensors, fp32 state/accum.  ws ~= 92.5 MiB.
// ---------------------------------------------------------------------------

typedef _Float16 f16;
typedef _Float16 f16x8 __attribute__((ext_vector_type(8)));
typedef float f32x4 __attribute__((ext_vector_type(4)));

#define DI __device__ __forceinline__

DI float sigm(float x) { return 1.f / (1.f + __expf(-x)); }
DI float tanh_(float x) { return 2.f / (1.f + __expf(-2.f * x)) - 1.f; }

#define GLDS16(g, l)                                                        \
  __builtin_amdgcn_global_load_lds(                                         \
      (const __attribute__((address_space(1))) void*)(const void*)(g),      \
      (__attribute__((address_space(3))) void*)(l), 16, 0, 0)

// ---------------- workspace layout ----------------------------------------
constexpr size_t O_EMBH  = 0;                    // f16 [32768][320]
constexpr size_t O_ENC   = O_EMBH  + 20971520;   // f16 [32768][1024]
constexpr size_t O_HBUF  = O_ENC   + 67108864;   // f16 [2dir][2buf][256][512]
constexpr size_t O_AW    = O_HBUF  + 1048576;    // f32 [32768][4]
constexpr size_t O_CTXW  = O_AW    + 524288;     // f32 [4][1024] + cb[4]
constexpr size_t O_SENTH = O_CTXW  + 16640;      // f16 [256][4096]
constexpr size_t O_XGS   = O_SENTH + 2097152;    // f32 [2][256][2048]
constexpr size_t O_HSBUF = O_XGS   + 4194304;    // f32 [2][2][512]
constexpr size_t O_OUTS  = O_HSBUF + 8192;       // f32 [256][1024]
constexpr size_t O_FLAGS = O_OUTS  + 1048576;    // int [512]
constexpr size_t TOTAL_WS = O_FLAGS + 2048;      // ~97,020,160 B

__global__ __launch_bounds__(256) void sentinel_kernel(float* out, int n) {
  for (int i = threadIdx.x; i < n; i += 256) out[i] = 1.0e4f;
}

// ---------------------------------------------------------------------------
// embedding gather + fp32->f16 cast, pad 300->320
// ---------------------------------------------------------------------------
__global__ __launch_bounds__(256) void embed_kernel(
    const int* __restrict__ tokens, const float* __restrict__ emb,
    f16* __restrict__ out) {
  const int row = blockIdx.x * 4 + (threadIdx.x >> 6);
  const int lane = threadIdx.x & 63;
  const long tok = tokens[row];
  const float* src = emb + tok * 300;
  f16* dst = out + (long)row * 320;
  for (int c = lane; c < 320; c += 64)
    dst[c] = (c < 300) ? (f16)src[c] : (f16)0.f;
}

// ---------------------------------------------------------------------------
// ctxW[h,e] = sum_a ctx[h,a]*W[a,e];  cb[h] = sum_a ctx[h,a]*b[a]
// ---------------------------------------------------------------------------
__global__ __launch_bounds__(256) void ctxw_kernel(
    const float* __restrict__ W, const float* __restrict__ b,
    const float* __restrict__ ctx, float* __restrict__ ctxW,
    float* __restrict__ cb) {
  const int h = blockIdx.x, tid = threadIdx.x;
  f32x4 acc = {0.f, 0.f, 0.f, 0.f};
  for (int a = 0; a < 256; ++a) {
    const float c = ctx[h * 256 + a];
    const f32x4 w4 = *(const f32x4*)&W[(long)a * 1024 + tid * 4];
    acc[0] += c * w4[0]; acc[1] += c * w4[1];
    acc[2] += c * w4[2]; acc[3] += c * w4[3];
  }
  *(f32x4*)&ctxW[h * 1024 + tid * 4] = acc;
  if (tid == 0) {
    float s = 0.f;
    for (int a = 0; a < 256; ++a) s += ctx[h * 256 + a] * b[a];
    cb[h] = s;
  }
}

// ---------------------------------------------------------------------------
// inter-WG barrier: release flag, poll peers (relaxed), acquire fence.
// ---------------------------------------------------------------------------
DI void wg_barrier(int* fl, int slot, int poll_idx, int target, int tid,
                   int wave) {
  __syncthreads();  // all block stores complete (vmcnt drained per thread)
  if (tid == 0)
    __hip_atomic_store(&fl[slot], target, __ATOMIC_RELEASE,
                       __HIP_MEMORY_SCOPE_AGENT);
  if (wave == 0) {
    while (__hip_atomic_load(&fl[poll_idx], __ATOMIC_RELAXED,
                             __HIP_MEMORY_SCOPE_AGENT) < target) {}
    __builtin_amdgcn_fence(__ATOMIC_ACQUIRE, "agent");
  }
  __syncthreads();
}

// ---------------------------------------------------------------------------
// token BiLSTM, persistent, input projection fused.
// grid 256 WGs x 512 thr.  wg: dir = wg>>7; mt = (wg&127)>>5 (64 sents);
// js = wg&31 (16 h-elems -> 64 gate rows {g*512+js*16+j}).
// LDS: Whh slice f16 [64][512] swz (64K) + Wih slice f16 [64][320] swz (40K)
//      + gbuf f32 [64][64] (16K) + bias (256B) = 123,136 B  -> 1 WG/CU.
// Per step: C[64 sent,64 gcol] = emb_t @ Wih^T + h_prev @ Whh^T via MFMA,
// exchange through gbuf, c/h update (c fp32 in regs), barrier over 32 WGs
// of the same (dir,mt).
// ---------------------------------------------------------------------------
constexpr int WIH_OFF = 65536;
constexpr int GBUF_OFF = 106496;
constexpr int BIAS_OFF = 122880;
constexpr int TOK_LDS = 123136;

__global__ __launch_bounds__(512) void tok_lstm(
    const f16* __restrict__ emb, const float* __restrict__ Whh_f,
    const float* __restrict__ Whh_b, const float* __restrict__ Wih_f,
    const float* __restrict__ Wih_b, const float* __restrict__ bih_f,
    const float* __restrict__ bhh_f, const float* __restrict__ bih_b,
    const float* __restrict__ bhh_b, f16* __restrict__ h_buf,
    f16* __restrict__ enc, int* __restrict__ flags) {
  extern __shared__ char smem[];
  float* gbuf = (float*)(smem + GBUF_OFF);
  float* bias_s = (float*)(smem + BIAS_OFF);
  const int wg = blockIdx.x;
  const int dir = wg >> 7, rest = wg & 127;
  const int mt = rest >> 5, js = rest & 31;
  const int tid = threadIdx.x, lane = tid & 63, wave = tid >> 6;
  const float* Whh = dir ? Whh_b : Whh_f;
  const float* Wih = dir ? Wih_b : Wih_f;
  const float* bih = dir ? bih_b : bih_f;
  const float* bhh = dir ? bhh_b : bhh_f;

  // ---- stage Whh slice fp32 -> f16, XOR-swizzled rows of 512 ----
  for (int idx = tid; idx < 64 * 64; idx += 512) {
    const int r = idx >> 6, c8 = idx & 63;
    const int grow = (r >> 4) * 512 + js * 16 + (r & 15);
    const float* src = Whh + (long)grow * 512 + c8 * 8;
    f16x8 v;
#pragma unroll
    for (int i = 0; i < 8; ++i) v[i] = (f16)src[i];
    *(f16x8*)(smem + ((r * 1024 + c8 * 16) ^ ((r & 7) << 4))) = v;
  }
  // ---- stage Wih slice fp32 [.,300] -> f16 [.,320] padded, swizzled ----
  for (int idx = tid; idx < 64 * 40; idx += 512) {
    const int r = idx / 40, c8 = idx % 40;
    const int grow = (r >> 4) * 512 + js * 16 + (r & 15);
    const int k0 = c8 * 8;
    f16x8 v;
#pragma unroll
    for (int i = 0; i < 8; ++i)
      v[i] = (k0 + i < 300) ? (f16)Wih[(long)grow * 300 + k0 + i] : (f16)0.f;
    *(f16x8*)(smem + WIH_OFF + ((r * 640 + c8 * 16) ^ ((r & 7) << 4))) = v;
  }
  if (tid < 64) {
    const int grow = (tid >> 4) * 512 + js * 16 + (tid & 15);
    bias_s[tid] = bih[grow] + bhh[grow];
  }
  __syncthreads();

  const int wm = wave & 1;   // sent half (32)
  const int wn = wave >> 1;  // gcol 16-block (0..3)
  const int al = lane & 15, koff = (lane >> 4) * 8;
  const int arow_base = mt * 64 + wm * 32;
  const int brow = wn * 16 + al;
  const int bswz = (brow & 7) << 4;
  // update mapping: thread owns (j = tid&15, 2 sents sg*2+{0,1})
  const int uj = tid & 15, sg = tid >> 4;
  float c_reg[2] = {0.f, 0.f};
  int* fl = flags + dir * 128 + mt * 32;
  const int poll_idx = lane & 31;

  for (int s = 0; s < 128; ++s) {
    const int t = dir ? (127 - s) : s;
    f32x4 acc0 = {0.f, 0.f, 0.f, 0.f}, acc1 = {0.f, 0.f, 0.f, 0.f};
    // ---- input projection: emb_t[64,320] @ Wih^T ----
    {
      const long e0 = ((long)(arow_base + al) * 128 + t) * 320;
      const long e1 = e0 + 16L * 128 * 320;
#pragma unroll
      for (int kt = 0; kt < 10; ++kt) {
        const f16x8 a0 = *(const f16x8*)&emb[e0 + kt * 32 + koff];
        const f16x8 a1 = *(const f16x8*)&emb[e1 + kt * 32 + koff];
        const f16x8 bf = *(const f16x8*)(
            smem + WIH_OFF + ((brow * 640 + kt * 64 + koff * 2) ^ bswz));
        acc0 = __builtin_amdgcn_mfma_f32_16x16x32_f16(a0, bf, acc0, 0, 0, 0);
        acc1 = __builtin_amdgcn_mfma_f32_16x16x32_f16(a1, bf, acc1, 0, 0, 0);
      }
    }
    // ---- recurrence: h_prev[64,512] @ Whh^T ----
    if (s > 0) {
      const f16* hb =
          h_buf + ((long)(dir * 2 + ((s - 1) & 1)) * 256 + arow_base) * 512;
#pragma unroll
      for (int kt = 0; kt < 16; ++kt) {
        const f16x8 a0 = *(const f16x8*)&hb[al * 512 + kt * 32 + koff];
        const f16x8 a1 = *(const f16x8*)&hb[(al + 16) * 512 + kt * 32 + koff];
        const f16x8 bf = *(const f16x8*)(
            smem + ((brow * 1024 + kt * 64 + koff * 2) ^ bswz));
        acc0 = __builtin_amdgcn_mfma_f32_16x16x32_f16(a0, bf, acc0, 0, 0, 0);
        acc1 = __builtin_amdgcn_mfma_f32_16x16x32_f16(a1, bf, acc1, 0, 0, 0);
      }
    }
    // ---- exchange C fragments through LDS ----
#pragma unroll
    for (int r = 0; r < 4; ++r) {
      gbuf[(wm * 32 + (lane >> 4) * 4 + r) * 64 + wn * 16 + al] = acc0[r];
      gbuf[(wm * 32 + 16 + (lane >> 4) * 4 + r) * 64 + wn * 16 + al] = acc1[r];
    }
    __syncthreads();
    // ---- gate nonlinearity + state update ----
#pragma unroll
    for (int e = 0; e < 2; ++e) {
      const int lr = sg * 2 + e;
      const float gi = gbuf[lr * 64 + uj] + bias_s[uj];
      const float gf = gbuf[lr * 64 + 16 + uj] + bias_s[16 + uj];
      const float gg = gbuf[lr * 64 + 32 + uj] + bias_s[32 + uj];
      const float go = gbuf[lr * 64 + 48 + uj] + bias_s[48 + uj];
      const float c = sigm(gf) * c_reg[e] + sigm(gi) * tanh_(gg);
      c_reg[e] = c;
      const float h = sigm(go) * tanh_(c);
      const int sent = mt * 64 + lr;
      h_buf[((long)(dir * 2 + (s & 1)) * 256 + sent) * 512 + js * 16 + uj] =
          (f16)h;
      enc[((long)sent * 128 + t) * 1024 + dir * 512 + js * 16 + uj] = (f16)h;
    }
    wg_barrier(fl, js, poll_idx, s + 1, tid, wave);
  }
}

// ---------------------------------------------------------------------------
// attention scores: p[h] = enc_row . ctxW[h] + cb[h]; softmax over 4 hops;
// zero rows past length; write aw[n,l,h].
// ---------------------------------------------------------------------------
__global__ __launch_bounds__(256) void attn_scores(
    const f16* __restrict__ enc, const float* __restrict__ ctxW,
    const float* __restrict__ cb, const int* __restrict__ lengths,
    float* __restrict__ aw) {
  const int row = blockIdx.x * 4 + (threadIdx.x >> 6);
  const int lane = threadIdx.x & 63;
  const f16* ep = enc + (long)row * 1024 + lane * 16;
  const f16x8 ev0 = *(const f16x8*)ep;
  const f16x8 ev1 = *(const f16x8*)(ep + 8);
  float ef[16];
#pragma unroll
  for (int i = 0; i < 8; ++i) { ef[i] = (float)ev0[i]; ef[8 + i] = (float)ev1[i]; }
  float p[4];
#pragma unroll
  for (int h = 0; h < 4; ++h) {
    const float* cw = ctxW + h * 1024 + lane * 16;
    float s = 0.f;
#pragma unroll
    for (int q = 0; q < 4; ++q) {
      const f32x4 c4 = *(const f32x4*)(cw + q * 4);
      s += ef[q * 4] * c4[0] + ef[q * 4 + 1] * c4[1] + ef[q * 4 + 2] * c4[2] +
           ef[q * 4 + 3] * c4[3];
    }
    p[h] = s;
  }
#pragma unroll
  for (int h = 0; h < 4; ++h)
#pragma unroll
    for (int off = 32; off; off >>= 1) p[h] += __shfl_xor(p[h], off);
  if (lane == 0) {
#pragma unroll
    for (int h = 0; h < 4; ++h) p[h] += cb[h];
    const float m = fmaxf(fmaxf(p[0], p[1]), fmaxf(p[2], p[3]));
    const float e0 = __expf(p[0] - m), e1 = __expf(p[1] - m),
                e2 = __expf(p[2] - m), e3 = __expf(p[3] - m);
    const int n = row >> 7, l = row & 127;
    const float keep = (l < lengths[n]) ? 1.f / (e0 + e1 + e2 + e3) : 0.f;
    ((f32x4*)aw)[row] = (f32x4){e0 * keep, e1 * keep, e2 * keep, e3 * keep};
  }
}

// sent[n, e*4+h] = sum_l enc[n,l,e] * aw[n,l,h]
__global__ __launch_bounds__(256) void attn_pool(const f16* __restrict__ enc,
                                                 const float* __restrict__ aw,
                                                 f16* __restrict__ sent) {
  const int n = blockIdx.x;
  __shared__ float aw_s[512];
  for (int i = threadIdx.x; i < 512; i += 256) aw_s[i] = aw[n * 512 + i];
  __syncthreads();
  const int e0 = threadIdx.x;
  float acc[4][4] = {};
  const f16* ep = enc + (long)n * 128 * 1024;
  for (int l = 0; l < 128; ++l) {
    const float a0 = aw_s[l * 4], a1 = aw_s[l * 4 + 1], a2 = aw_s[l * 4 + 2],
                a3 = aw_s[l * 4 + 3];
#pragma unroll
    for (int q = 0; q < 4; ++q) {
      const float evx = (float)ep[l * 1024 + e0 + q * 256];
      acc[q][0] += evx * a0;
      acc[q][1] += evx * a1;
      acc[q][2] += evx * a2;
      acc[q][3] += evx * a3;
    }
  }
#pragma unroll
  for (int q = 0; q < 4; ++q) {
    const int e = e0 + q * 256;
#pragma unroll
    for (int h = 0; h < 4; ++h) sent[(long)n * 4096 + e * 4 + h] = (f16)acc[q][h];
  }
}

// ---------------------------------------------------------------------------
// GEMM C[M,N] = A[M,K](f16) * B[N,K](fp32)^T -> f32.  128x128 tile, 4 waves.
// A staged via global_load_lds; B staged via regs with fp32->f16 convert.
// ---------------------------------------------------------------------------
__global__ __launch_bounds__(256) void gemm_a16_b32(
    const f16* __restrict__ A, const float* __restrict__ B,
    float* __restrict__ C, int M, int N, int K, int lda, int ldb, int ldc) {
  __shared__ f16 As[128 * 32];
  __shared__ f16 Bs[128 * 32];
  const int tid = threadIdx.x;
  const int lane = tid & 63, wave = tid >> 6;
  const int bm = blockIdx.x, bn = blockIdx.y;
  const int wm = (wave >> 1) * 64, wn = (wave & 1) * 64;
  f32x4 acc[4][4] = {};
  const long arow0 = (long)bm * 128;
  const long brow0 = (long)bn * 128;
  const int r_half = tid >> 2;       // 0..63
  const int c_half = (tid & 3) * 8;  // 0,8,16,24
  const int brow_s = tid >> 1, bcol_s = (tid & 1) * 16;
  const int KT = K >> 5;
  for (int kt = 0; kt < KT; ++kt) {
    const int k0 = kt << 5;
#pragma unroll
    for (int i = 0; i < 2; ++i)
      GLDS16(A + (arow0 + i * 64 + r_half) * lda + k0 + c_half,
             (char*)As + i * 4096 + tid * 16);
    {
      const float* bp = B + (brow0 + brow_s) * (long)ldb + k0 + bcol_s;
      f16x8 lo, hi;
#pragma unroll
      for (int i = 0; i < 8; ++i) { lo[i] = (f16)bp[i]; hi[i] = (f16)bp[8 + i]; }
      *(f16x8*)&Bs[brow_s * 32 + bcol_s] = lo;
      *(f16x8*)&Bs[brow_s * 32 + bcol_s + 8] = hi;
    }
    __syncthreads();
    f16x8 af[4], bf[4];
    const int kr = (lane >> 4) * 8;
#pragma unroll
    for (int f = 0; f < 4; ++f) {
      af[f] = *(const f16x8*)&As[(wm + f * 16 + (lane & 15)) * 32 + kr];
      bf[f] = *(const f16x8*)&Bs[(wn + f * 16 + (lane & 15)) * 32 + kr];
    }
#pragma unroll
    for (int a = 0; a < 4; ++a)
#pragma unroll
      for (int b = 0; b < 4; ++b)
        acc[a][b] =
            __builtin_amdgcn_mfma_f32_16x16x32_f16(af[a], bf[b], acc[a][b], 0, 0, 0);
    __syncthreads();
  }
#pragma unroll
  for (int a = 0; a < 4; ++a)
#pragma unroll
    for (int r = 0; r < 4; ++r) {
      const long row = arow0 + wm + a * 16 + (lane >> 4) * 4 + r;
#pragma unroll
      for (int b = 0; b < 4; ++b) {
        const int col = bn * 128 + wn + b * 16 + (lane & 15);
        C[row * (long)ldc + col] = acc[a][b][r];
      }
    }
}

// ---------------------------------------------------------------------------
// sentence BiLSTM, persistent.  grid 128 WGs x 256 thr.
// dir = wg>>6; w = wg&63 owns 8 h-elems (32 gate rows).  W slice f16
// k-major [512][33] in static LDS (~37 KB).  fp32 matvec, flag barrier
// over the dir's 64 WGs per step.
// ---------------------------------------------------------------------------
__global__ __launch_bounds__(256) void sent_lstm(
    const float* __restrict__ xgs, const float* __restrict__ Whh_f,
    const float* __restrict__ Whh_b, const float* __restrict__ bih_f,
    const float* __restrict__ bhh_f, const float* __restrict__ bih_b,
    const float* __restrict__ bhh_b, float* __restrict__ h_buf,
    float* __restrict__ outp, int* __restrict__ flags) {
  __shared__ f16 Ws[512 * 33];
  __shared__ float h_s[512];
  __shared__ float partials[256];
  __shared__ float gates_s[32];
  __shared__ float bias_s[32];
  const int wg = blockIdx.x;
  const int dir = wg >> 6, w = wg & 63;
  const int tid = threadIdx.x, lane = tid & 63, wave = tid >> 6;
  const float* Whh = dir ? Whh_b : Whh_f;
  const float* bih = dir ? bih_b : bih_f;
  const float* bhh = dir ? bhh_b : bhh_f;
  const float* xg = xgs + (long)dir * 256 * 2048;

  for (int r = 0; r < 32; ++r) {
    const int grow = (r >> 3) * 512 + w * 8 + (r & 7);
    for (int k = tid; k < 512; k += 256)
      Ws[k * 33 + r] = (f16)Whh[(long)grow * 512 + k];
  }
  if (tid < 32) {
    const int grow = (tid >> 3) * 512 + w * 8 + (tid & 7);
    bias_s[tid] = bih[grow] + bhh[grow];
  }
  __syncthreads();

  const int o = tid & 31, kq = tid >> 5;
  float c_reg = 0.f;
  int* fl = flags + 256 + dir * 64;
  const int poll_idx = lane & 63;

  for (int s = 0; s < 256; ++s) {
    const int seq = dir ? (255 - s) : s;
    if (s > 0) {
      const float* hsrc = h_buf + (dir * 2 + ((s - 1) & 1)) * 512;
      if (tid < 128) ((f32x4*)h_s)[tid] = ((const f32x4*)hsrc)[tid];
      __syncthreads();
      float acc = 0.f;
#pragma unroll 8
      for (int i = 0; i < 64; ++i) {
        const int kc = kq * 64 + i;
        acc += (float)Ws[kc * 33 + o] * h_s[kc];
      }
      partials[tid] = acc;
      __syncthreads();
      if (tid < 32) {
        float g = 0.f;
#pragma unroll
        for (int q = 0; q < 8; ++q) g += partials[q * 32 + tid];
        gates_s[tid] = g;
      }
    } else {
      if (tid < 32) gates_s[tid] = 0.f;
    }
    __syncthreads();
    if (tid < 8) {
      const int j = tid;
      const long xb = (long)seq * 2048 + w * 8 + j;
      const float gi = gates_s[j] + bias_s[j] + xg[xb];
      const float gf = gates_s[8 + j] + bias_s[8 + j] + xg[xb + 512];
      const float gg = gates_s[16 + j] + bias_s[16 + j] + xg[xb + 1024];
      const float go = gates_s[24 + j] + bias_s[24 + j] + xg[xb + 1536];
      const float c = sigm(gf) * c_reg + sigm(gi) * tanh_(gg);
      c_reg = c;
      const float h = sigm(go) * tanh_(c);
      h_buf[(dir * 2 + (s & 1)) * 512 + w * 8 + j] = h;
      outp[(long)seq * 1024 + dir * 512 + w * 8 + j] = h;
    }
    wg_barrier(fl, w, poll_idx, s + 1, tid, wave);
  }
}

// ---------------------------------------------------------------------------
__global__ __launch_bounds__(64) void final_linear(const float* __restrict__ hin,
                                                   const float* __restrict__ W,
                                                   const float* __restrict__ b,
                                                   float* __restrict__ out) {
  const int row = blockIdx.x, lane = threadIdx.x;
  float p[7] = {};
  for (int k = lane; k < 1024; k += 64) {
    const float hv = hin[row * 1024 + k];
#pragma unroll
    for (int oo = 0; oo < 7; ++oo) p[oo] += hv * W[oo * 1024 + k];
  }
#pragma unroll
  for (int oo = 0; oo < 7; ++oo)
#pragma unroll
    for (int off = 32; off; off >>= 1) p[oo] += __shfl_xor(p[oo], off);
  if (lane == 0)
#pragma unroll
    for (int oo = 0; oo < 7; ++oo) out[row * 7 + oo] = p[oo] + b[oo];
}

// ---------------------------------------------------------------------------
extern "C" void kernel_launch(void* const* d_in, const int* in_sizes, int n_in,
                              void* d_out, int out_size, void* d_ws,
                              size_t ws_size, hipStream_t stream) {
  const int* tokens = (const int*)d_in[0];
  const int* lengths = (const int*)d_in[1];
  const float* embed = (const float*)d_in[2];
  const float* tWih_f = (const float*)d_in[3];
  const float* tWhh_f = (const float*)d_in[4];
  const float* tbih_f = (const float*)d_in[5];
  const float* tbhh_f = (const float*)d_in[6];
  const float* tWih_b = (const float*)d_in[7];
  const float* tWhh_b = (const float*)d_in[8];
  const float* tbih_b = (const float*)d_in[9];
  const float* tbhh_b = (const float*)d_in[10];
  const float* attnW = (const float*)d_in[11];
  const float* attnB = (const float*)d_in[12];
  const float* attnCtx = (const float*)d_in[13];
  const float* sWih_f = (const float*)d_in[14];
  const float* sWhh_f = (const float*)d_in[15];
  const float* sbih_f = (const float*)d_in[16];
  const float* sbhh_f = (const float*)d_in[17];
  const float* sWih_b = (const float*)d_in[18];
  const float* sWhh_b = (const float*)d_in[19];
  const float* sbih_b = (const float*)d_in[20];
  const float* sbhh_b = (const float*)d_in[21];
  const float* linW = (const float*)d_in[22];
  const float* linB = (const float*)d_in[23];
  float* out = (float*)d_out;
  char* ws = (char*)d_ws;
  if (ws_size < TOTAL_WS) {  // diagnosable sentinel: absmax ~1e4 => ws too small
    sentinel_kernel<<<1, 256, 0, stream>>>(out, out_size);
    return;
  }

  f16* emb_h = (f16*)(ws + O_EMBH);
  f16* enc = (f16*)(ws + O_ENC);
  f16* h_buf = (f16*)(ws + O_HBUF);
  float* aw = (float*)(ws + O_AW);
  float* ctxW = (float*)(ws + O_CTXW);
  float* cb = ctxW + 4096;
  f16* sent_h = (f16*)(ws + O_SENTH);
  float* xgs = (float*)(ws + O_XGS);
  float* hs_buf = (float*)(ws + O_HSBUF);
  float* out_sent = (float*)(ws + O_OUTS);
  int* flags = (int*)(ws + O_FLAGS);

  hipFuncSetAttribute((const void*)tok_lstm,
                      hipFuncAttributeMaxDynamicSharedMemorySize, TOK_LDS);

  hipMemsetAsync(ws + O_FLAGS, 0, 2048, stream);

  embed_kernel<<<8192, 256, 0, stream>>>(tokens, embed, emb_h);
  ctxw_kernel<<<4, 256, 0, stream>>>(attnW, attnB, attnCtx, ctxW, cb);

  // token BiLSTM (persistent, fused input projection)
  tok_lstm<<<256, 512, TOK_LDS, stream>>>(
      emb_h, tWhh_f, tWhh_b, tWih_f, tWih_b, tbih_f, tbhh_f, tbih_b, tbhh_b,
      h_buf, enc, flags);

  // attention
  attn_scores<<<8192, 256, 0, stream>>>(enc, ctxW, cb, lengths, aw);
  attn_pool<<<256, 256, 0, stream>>>(enc, aw, sent_h);

  // sentence LSTM input projections (B = fp32 weights, converted in staging)
  gemm_a16_b32<<<dim3(2, 16), 256, 0, stream>>>(
      sent_h, sWih_f, xgs, 256, 2048, 4096, 4096, 4096, 2048);
  gemm_a16_b32<<<dim3(2, 16), 256, 0, stream>>>(
      sent_h, sWih_b, xgs + 256 * 2048, 256, 2048, 4096, 4096, 4096, 2048);

  // sentence BiLSTM (persistent)
  sent_lstm<<<128, 256, 0, stream>>>(xgs, sWhh_f, sWhh_b, sbih_f, sbhh_f,
                                     sbih_b, sbhh_b, hs_buf, out_sent, flags);

  final_linear<<<256, 64, 0, stream>>>(out_sent, linW, linB, out);
}

// Round 3
// 4212.300 us; speedup vs baseline: 1.2045x; 1.2045x over previous
//
#include <hip/hip_runtime.h>

// ---------------------------------------------------------------------------
// SentenceClassifier: emb -> token BiLSTM (fused input proj, persistent)
// -> folded hop attention -> sentence BiLSTM (persistent) -> linear.
// fp16 MFMA/storage, fp32 state/accum.  Cross-WG exchange via per-access
// agent-scope atomics (sc1) -- NO agent fences (no buffer_wbl2/inv L2 nukes).
// ---------------------------------------------------------------------------

typedef _Float16 f16;
typedef _Float16 f16x8 __attribute__((ext_vector_type(8)));
typedef float f32x4 __attribute__((ext_vector_type(4)));
typedef unsigned int u32x4 __attribute__((ext_vector_type(4)));

#define DI __device__ __forceinline__

DI float sigm(float x) { return 1.f / (1.f + __expf(-x)); }
DI float tanh_(float x) { return 2.f / (1.f + __expf(-2.f * x)) - 1.f; }

// device-coherent (cross-XCD) word access: relaxed atomics at agent scope.
// Emits global_load/store_dword with sc1 -- bypasses the non-coherent per-XCD
// L2 for exactly these accesses; plain cached loads stay warm in L2.
DI void st_dev(unsigned int* p, unsigned int v) {
  __hip_atomic_store(p, v, __ATOMIC_RELAXED, __HIP_MEMORY_SCOPE_AGENT);
}
DI unsigned int ld_dev(const unsigned int* p) {
  return __hip_atomic_load(p, __ATOMIC_RELAXED, __HIP_MEMORY_SCOPE_AGENT);
}

#define MFMA16(a, b, c) __builtin_amdgcn_mfma_f32_16x16x32_f16(a, b, c, 0, 0, 0)

// ---------------- workspace layout ----------------------------------------
constexpr size_t O_EMBH  = 0;                    // f16 [32768][320]
constexpr size_t O_ENC   = O_EMBH  + 20971520;   // f16 [32768][1024]
constexpr size_t O_HBUF  = O_ENC   + 67108864;   // f16 [2dir][2buf][256][512]
constexpr size_t O_AW    = O_HBUF  + 1048576;    // f32 [32768][4]
constexpr size_t O_CTXW  = O_AW    + 524288;     // f32 [4][1024] + cb[4]
constexpr size_t O_SENTH = O_CTXW  + 16640;      // f16 [256][4096]
constexpr size_t O_XGS   = O_SENTH + 2097152;    // f32 [2][256][2048]
constexpr size_t O_HSBUF = O_XGS   + 4194304;    // f32 [2][2][512]
constexpr size_t O_OUTS  = O_HSBUF + 8192;       // f32 [256][1024]
constexpr size_t O_FLAGS = O_OUTS  + 1048576;    // int [512]
constexpr size_t TOTAL_WS = O_FLAGS + 2048;

__global__ __launch_bounds__(256) void sentinel_kernel(float* out, int n) {
  for (int i = threadIdx.x; i < n; i += 256) out[i] = 1.0e4f;
}

// ---------------------------------------------------------------------------
__global__ __launch_bounds__(256) void embed_kernel(
    const int* __restrict__ tokens, const float* __restrict__ emb,
    f16* __restrict__ out) {
  const int row = blockIdx.x * 4 + (threadIdx.x >> 6);
  const int lane = threadIdx.x & 63;
  const long tok = tokens[row];
  const float* src = emb + tok * 300;
  f16* dst = out + (long)row * 320;
  for (int c = lane; c < 320; c += 64)
    dst[c] = (c < 300) ? (f16)src[c] : (f16)0.f;
}

// ---------------------------------------------------------------------------
// ctxW[h,e] = sum_a ctx[h,a]*W[a,e];  cb[h] = sum_a ctx[h,a]*b[a]
// ---------------------------------------------------------------------------
__global__ __launch_bounds__(256) void ctxw_kernel(
    const float* __restrict__ W, const float* __restrict__ b,
    const float* __restrict__ ctx, float* __restrict__ ctxW,
    float* __restrict__ cb) {
  const int h = blockIdx.x, tid = threadIdx.x;
  f32x4 acc = {0.f, 0.f, 0.f, 0.f};
  for (int a = 0; a < 256; ++a) {
    const float c = ctx[h * 256 + a];
    const f32x4 w4 = *(const f32x4*)&W[(long)a * 1024 + tid * 4];
    acc[0] += c * w4[0]; acc[1] += c * w4[1];
    acc[2] += c * w4[2]; acc[3] += c * w4[3];
  }
  *(f32x4*)&ctxW[h * 1024 + tid * 4] = acc;
  if (tid == 0) {
    float s = 0.f;
    for (int a = 0; a < 256; ++a) s += ctx[h * 256 + a] * b[a];
    cb[h] = s;
  }
}

// ---------------------------------------------------------------------------
// inter-WG barrier: drain stores (__syncthreads waits vmcnt per thread),
// relaxed agent flag store, relaxed poll.  NO cache-maintenance fences --
// all cross-WG data moves via sc1 atomics which are self-coherent.
// ---------------------------------------------------------------------------
DI void wg_barrier(int* fl, int slot, int poll_idx, int target, int tid,
                   int wave) {
  __syncthreads();
  if (tid == 0)
    __hip_atomic_store(&fl[slot], target, __ATOMIC_RELAXED,
                       __HIP_MEMORY_SCOPE_AGENT);
  if (wave == 0) {
    while (__hip_atomic_load(&fl[poll_idx], __ATOMIC_RELAXED,
                             __HIP_MEMORY_SCOPE_AGENT) < target) {}
  }
  __syncthreads();
}

// ---------------------------------------------------------------------------
// token BiLSTM, persistent, input projection fused.
// grid 256 WGs x 512 thr.  dir = wg>>7; mt = (wg&127)>>5 (64-sent tile);
// js = wg&31 (16 h-elems -> 64 gate cols {g*512 + js*16 + j}).
// Waves: wm = wave>>2? no: wm = wave>>1 (4 groups of 16 sents), wn = wave&1
// (2 groups of 32 gate cols) -> no duplicated h loads across waves.
// LDS: Whh [64][512] f16 swz + Wih [64][320] f16 swz + gbuf f32[64][64]
//      + bias[64] = 123,136 B -> 1 WG/CU.
// h exchange via agent-scope atomic dwords (f16 pairs), double-buffered.
// ---------------------------------------------------------------------------
constexpr int WIH_OFF = 65536;
constexpr int GBUF_OFF = 106496;
constexpr int BIAS_OFF = 122880;
constexpr int TOK_LDS = 123136;

__global__ __launch_bounds__(512) void tok_lstm(
    const f16* __restrict__ emb, const float* __restrict__ Whh_f,
    const float* __restrict__ Whh_b, const float* __restrict__ Wih_f,
    const float* __restrict__ Wih_b, const float* __restrict__ bih_f,
    const float* __restrict__ bhh_f, const float* __restrict__ bih_b,
    const float* __restrict__ bhh_b, unsigned int* __restrict__ hbw,
    f16* __restrict__ enc, int* __restrict__ flags) {
  extern __shared__ char smem[];
  float* gbuf = (float*)(smem + GBUF_OFF);
  float* bias_s = (float*)(smem + BIAS_OFF);
  const int wg = blockIdx.x;
  const int dir = wg >> 7, rest = wg & 127;
  const int mt = rest >> 5, js = rest & 31;
  const int tid = threadIdx.x, lane = tid & 63, wave = tid >> 6;
  const float* Whh = dir ? Whh_b : Whh_f;
  const float* Wih = dir ? Wih_b : Wih_f;
  const float* bih = dir ? bih_b : bih_f;
  const float* bhh = dir ? bhh_b : bhh_f;

  // ---- stage Whh slice fp32 -> f16, XOR-swizzled rows of 512 ----
  for (int idx = tid; idx < 64 * 64; idx += 512) {
    const int r = idx >> 6, c8 = idx & 63;
    const int grow = (r >> 4) * 512 + js * 16 + (r & 15);
    const float* src = Whh + (long)grow * 512 + c8 * 8;
    f16x8 v;
#pragma unroll
    for (int i = 0; i < 8; ++i) v[i] = (f16)src[i];
    *(f16x8*)(smem + ((r * 1024 + c8 * 16) ^ ((r & 7) << 4))) = v;
  }
  // ---- stage Wih slice fp32 [.,300] -> f16 [.,320] padded, swizzled ----
  for (int idx = tid; idx < 64 * 40; idx += 512) {
    const int r = idx / 40, c8 = idx % 40;
    const int grow = (r >> 4) * 512 + js * 16 + (r & 15);
    const int k0 = c8 * 8;
    f16x8 v;
#pragma unroll
    for (int i = 0; i < 8; ++i)
      v[i] = (k0 + i < 300) ? (f16)Wih[(long)grow * 300 + k0 + i] : (f16)0.f;
    *(f16x8*)(smem + WIH_OFF + ((r * 640 + c8 * 16) ^ ((r & 7) << 4))) = v;
  }
  if (tid < 64) {
    const int grow = (tid >> 4) * 512 + js * 16 + (tid & 15);
    bias_s[tid] = bih[grow] + bhh[grow];
  }
  __syncthreads();

  const int wm = wave >> 1;  // 0..3: 16-sent group
  const int wn = wave & 1;   // 0..1: 32-gcol group
  const int al = lane & 15, kq = lane >> 4;
  const int arow = mt * 64 + wm * 16 + al;
  const int lr = tid >> 3, jp = tid & 7;  // update: sent-local lr, j-pair jp
  float c0 = 0.f, c1 = 0.f;
  int* fl = flags + dir * 128 + mt * 32;
  const int poll_idx = lane & 31;

  for (int s = 0; s < 128; ++s) {
    const int t = dir ? 127 - s : s;
    // ---- issue coherent h loads first (hide fabric latency) ----
    unsigned int aw[64];
    if (s > 0) {
      const int base =
          ((dir * 2 + ((s - 1) & 1)) * 256 + arow) * 256 + kq * 4;
#pragma unroll
      for (int kt = 0; kt < 16; ++kt)
#pragma unroll
        for (int w2 = 0; w2 < 4; ++w2)
          aw[kt * 4 + w2] = ld_dev(&hbw[base + kt * 16 + w2]);
    }
    f32x4 acc[2] = {{0.f, 0.f, 0.f, 0.f}, {0.f, 0.f, 0.f, 0.f}};
    // ---- input projection: emb_t[16,320] @ Wih^T ----
    {
      const long e0 = ((long)arow * 128 + t) * 320 + kq * 8;
#pragma unroll
      for (int kt = 0; kt < 10; ++kt) {
        const f16x8 a = *(const f16x8*)&emb[e0 + kt * 32];
#pragma unroll
        for (int fb = 0; fb < 2; ++fb) {
          const int brow = wn * 32 + fb * 16 + al;
          const f16x8 bf = *(const f16x8*)(
              smem + WIH_OFF +
              ((brow * 640 + kt * 64 + kq * 16) ^ ((brow & 7) << 4)));
          acc[fb] = MFMA16(a, bf, acc[fb]);
        }
      }
    }
    // ---- recurrence: h_prev[16,512] @ Whh^T ----
    if (s > 0) {
#pragma unroll
      for (int kt = 0; kt < 16; ++kt) {
        u32x4 wv = {aw[kt * 4], aw[kt * 4 + 1], aw[kt * 4 + 2], aw[kt * 4 + 3]};
        const f16x8 a = __builtin_bit_cast(f16x8, wv);
#pragma unroll
        for (int fb = 0; fb < 2; ++fb) {
          const int brow = wn * 32 + fb * 16 + al;
          const f16x8 bf = *(const f16x8*)(
              smem + ((brow * 1024 + kt * 64 + kq * 16) ^ ((brow & 7) << 4)));
          acc[fb] = MFMA16(a, bf, acc[fb]);
        }
      }
    }
    // ---- exchange C fragments through LDS ----
#pragma unroll
    for (int fb = 0; fb < 2; ++fb)
#pragma unroll
      for (int r = 0; r < 4; ++r)
        gbuf[(wm * 16 + kq * 4 + r) * 64 + wn * 32 + fb * 16 + al] =
            acc[fb][r];
    __syncthreads();
    // ---- gate nonlinearity + state update: thread owns (lr, j=2jp,2jp+1) --
    {
      const int j0 = jp * 2;
      const float i0 = gbuf[lr * 64 + j0] + bias_s[j0];
      const float i1 = gbuf[lr * 64 + j0 + 1] + bias_s[j0 + 1];
      const float f0 = gbuf[lr * 64 + 16 + j0] + bias_s[16 + j0];
      const float f1 = gbuf[lr * 64 + 16 + j0 + 1] + bias_s[16 + j0 + 1];
      const float g0 = gbuf[lr * 64 + 32 + j0] + bias_s[32 + j0];
      const float g1 = gbuf[lr * 64 + 32 + j0 + 1] + bias_s[32 + j0 + 1];
      const float o0 = gbuf[lr * 64 + 48 + j0] + bias_s[48 + j0];
      const float o1 = gbuf[lr * 64 + 48 + j0 + 1] + bias_s[48 + j0 + 1];
      c0 = sigm(f0) * c0 + sigm(i0) * tanh_(g0);
      c1 = sigm(f1) * c1 + sigm(i1) * tanh_(g1);
      const float h0 = sigm(o0) * tanh_(c0);
      const float h1 = sigm(o1) * tanh_(c1);
      union { f16 h2[2]; unsigned int u; } pk;
      pk.h2[0] = (f16)h0; pk.h2[1] = (f16)h1;
      const int sent = mt * 64 + lr;
      st_dev(&hbw[((dir * 2 + (s & 1)) * 256 + sent) * 256 + js * 8 + jp],
             pk.u);
      ((unsigned int*)enc)[((long)sent * 128 + t) * 512 + dir * 256 + js * 8 +
                           jp] = pk.u;
    }
    wg_barrier(fl, js, poll_idx, s + 1, tid, wave);
  }
}

// ---------------------------------------------------------------------------
// attention scores: p[h] = enc_row . ctxW[h] + cb[h]; softmax over 4 hops;
// zero rows past length.
// ---------------------------------------------------------------------------
__global__ __launch_bounds__(256) void attn_scores(
    const f16* __restrict__ enc, const float* __restrict__ ctxW,
    const float* __restrict__ cb, const int* __restrict__ lengths,
    float* __restrict__ aw) {
  const int row = blockIdx.x * 4 + (threadIdx.x >> 6);
  const int lane = threadIdx.x & 63;
  const f16* ep = enc + (long)row * 1024 + lane * 16;
  const f16x8 ev0 = *(const f16x8*)ep;
  const f16x8 ev1 = *(const f16x8*)(ep + 8);
  float ef[16];
#pragma unroll
  for (int i = 0; i < 8; ++i) { ef[i] = (float)ev0[i]; ef[8 + i] = (float)ev1[i]; }
  float p[4];
#pragma unroll
  for (int h = 0; h < 4; ++h) {
    const float* cw = ctxW + h * 1024 + lane * 16;
    float s = 0.f;
#pragma unroll
    for (int q = 0; q < 4; ++q) {
      const f32x4 c4 = *(const f32x4*)(cw + q * 4);
      s += ef[q * 4] * c4[0] + ef[q * 4 + 1] * c4[1] + ef[q * 4 + 2] * c4[2] +
           ef[q * 4 + 3] * c4[3];
    }
    p[h] = s;
  }
#pragma unroll
  for (int h = 0; h < 4; ++h)
#pragma unroll
    for (int off = 32; off; off >>= 1) p[h] += __shfl_xor(p[h], off);
  if (lane == 0) {
#pragma unroll
    for (int h = 0; h < 4; ++h) p[h] += cb[h];
    const float m = fmaxf(fmaxf(p[0], p[1]), fmaxf(p[2], p[3]));
    const float e0 = __expf(p[0] - m), e1 = __expf(p[1] - m),
                e2 = __expf(p[2] - m), e3 = __expf(p[3] - m);
    const int n = row >> 7, l = row & 127;
    const float keep = (l < lengths[n]) ? 1.f / (e0 + e1 + e2 + e3) : 0.f;
    ((f32x4*)aw)[row] = (f32x4){e0 * keep, e1 * keep, e2 * keep, e3 * keep};
  }
}

// sent[n, e*4+h] = sum_l enc[n,l,e] * aw[n,l,h]
__global__ __launch_bounds__(256) void attn_pool(const f16* __restrict__ enc,
                                                 const float* __restrict__ aw,
                                                 f16* __restrict__ sent) {
  const int n = blockIdx.x;
  __shared__ float aw_s[512];
  for (int i = threadIdx.x; i < 512; i += 256) aw_s[i] = aw[n * 512 + i];
  __syncthreads();
  const int e0 = threadIdx.x;
  float acc[4][4] = {};
  const f16* ep = enc + (long)n * 128 * 1024;
  for (int l = 0; l < 128; ++l) {
    const float a0 = aw_s[l * 4], a1 = aw_s[l * 4 + 1], a2 = aw_s[l * 4 + 2],
                a3 = aw_s[l * 4 + 3];
#pragma unroll
    for (int q = 0; q < 4; ++q) {
      const float evx = (float)ep[l * 1024 + e0 + q * 256];
      acc[q][0] += evx * a0;
      acc[q][1] += evx * a1;
      acc[q][2] += evx * a2;
      acc[q][3] += evx * a3;
    }
  }
#pragma unroll
  for (int q = 0; q < 4; ++q) {
    const int e = e0 + q * 256;
#pragma unroll
    for (int h = 0; h < 4; ++h) sent[(long)n * 4096 + e * 4 + h] = (f16)acc[q][h];
  }
}

// ---------------------------------------------------------------------------
// GEMM C[M,N] = A[M,K](f16) * B[N,K](fp32)^T -> f32.  128x128 tile, 4 waves.
// ---------------------------------------------------------------------------
#define GLDS16(g, l)                                                        \
  __builtin_amdgcn_global_load_lds(                                         \
      (const __attribute__((address_space(1))) void*)(const void*)(g),      \
      (__attribute__((address_space(3))) void*)(l), 16, 0, 0)

__global__ __launch_bounds__(256) void gemm_a16_b32(
    const f16* __restrict__ A, const float* __restrict__ B,
    float* __restrict__ C, int M, int N, int K, int lda, int ldb, int ldc) {
  __shared__ f16 As[128 * 32];
  __shared__ f16 Bs[128 * 32];
  const int tid = threadIdx.x;
  const int lane = tid & 63, wave = tid >> 6;
  const int bm = blockIdx.x, bn = blockIdx.y;
  const int wm = (wave >> 1) * 64, wn = (wave & 1) * 64;
  f32x4 acc[4][4] = {};
  const long arow0 = (long)bm * 128;
  const long brow0 = (long)bn * 128;
  const int r_half = tid >> 2;
  const int c_half = (tid & 3) * 8;
  const int brow_s = tid >> 1, bcol_s = (tid & 1) * 16;
  const int KT = K >> 5;
  for (int kt = 0; kt < KT; ++kt) {
    const int k0 = kt << 5;
#pragma unroll
    for (int i = 0; i < 2; ++i)
      GLDS16(A + (arow0 + i * 64 + r_half) * lda + k0 + c_half,
             (char*)As + i * 4096 + tid * 16);
    {
      const float* bp = B + (brow0 + brow_s) * (long)ldb + k0 + bcol_s;
      f16x8 lo, hi;
#pragma unroll
      for (int i = 0; i < 8; ++i) { lo[i] = (f16)bp[i]; hi[i] = (f16)bp[8 + i]; }
      *(f16x8*)&Bs[brow_s * 32 + bcol_s] = lo;
      *(f16x8*)&Bs[brow_s * 32 + bcol_s + 8] = hi;
    }
    __syncthreads();
    f16x8 af[4], bf[4];
    const int kr = (lane >> 4) * 8;
#pragma unroll
    for (int f = 0; f < 4; ++f) {
      af[f] = *(const f16x8*)&As[(wm + f * 16 + (lane & 15)) * 32 + kr];
      bf[f] = *(const f16x8*)&Bs[(wn + f * 16 + (lane & 15)) * 32 + kr];
    }
#pragma unroll
    for (int a = 0; a < 4; ++a)
#pragma unroll
      for (int b = 0; b < 4; ++b)
        acc[a][b] = MFMA16(af[a], bf[b], acc[a][b]);
    __syncthreads();
  }
#pragma unroll
  for (int a = 0; a < 4; ++a)
#pragma unroll
    for (int r = 0; r < 4; ++r) {
      const long row = arow0 + wm + a * 16 + (lane >> 4) * 4 + r;
#pragma unroll
      for (int b = 0; b < 4; ++b) {
        const int col = bn * 128 + wn + b * 16 + (lane & 15);
        C[row * (long)ldc + col] = acc[a][b][r];
      }
    }
}

// ---------------------------------------------------------------------------
// sentence BiLSTM, persistent.  grid 128 WGs x 256 thr.
// dir = wg>>6; w = wg&63 owns 8 h-elems (32 gate rows).  W slice f16
// k-major [512][33] in static LDS.  h exchange via agent atomics.
// ---------------------------------------------------------------------------
__global__ __launch_bounds__(256) void sent_lstm(
    const float* __restrict__ xgs, const float* __restrict__ Whh_f,
    const float* __restrict__ Whh_b, const float* __restrict__ bih_f,
    const float* __restrict__ bhh_f, const float* __restrict__ bih_b,
    const float* __restrict__ bhh_b, unsigned int* __restrict__ hsw,
    float* __restrict__ outp, int* __restrict__ flags) {
  __shared__ f16 Ws[512 * 33];
  __shared__ float h_s[512];
  __shared__ float partials[256];
  __shared__ float gates_s[32];
  __shared__ float bias_s[32];
  const int wg = blockIdx.x;
  const int dir = wg >> 6, w = wg & 63;
  const int tid = threadIdx.x, lane = tid & 63, wave = tid >> 6;
  const float* Whh = dir ? Whh_b : Whh_f;
  const float* bih = dir ? bih_b : bih_f;
  const float* bhh = dir ? bhh_b : bhh_f;
  const float* xg = xgs + (long)dir * 256 * 2048;

  for (int r = 0; r < 32; ++r) {
    const int grow = (r >> 3) * 512 + w * 8 + (r & 7);
    for (int k = tid; k < 512; k += 256)
      Ws[k * 33 + r] = (f16)Whh[(long)grow * 512 + k];
  }
  if (tid < 32) {
    const int grow = (tid >> 3) * 512 + w * 8 + (tid & 7);
    bias_s[tid] = bih[grow] + bhh[grow];
  }
  __syncthreads();

  const int o = tid & 31, kq = tid >> 5;
  float c_reg = 0.f;
  int* fl = flags + 256 + dir * 64;
  const int poll_idx = lane & 63;

  for (int s = 0; s < 256; ++s) {
    const int seq = dir ? (255 - s) : s;
    if (s > 0) {
      const int hb = (dir * 2 + ((s - 1) & 1)) * 512;
      for (int q = tid; q < 512; q += 256) {
        const unsigned int u = ld_dev(&hsw[hb + q]);
        h_s[q] = __builtin_bit_cast(float, u);
      }
      __syncthreads();
      float acc = 0.f;
#pragma unroll 8
      for (int i = 0; i < 64; ++i) {
        const int kc = kq * 64 + i;
        acc += (float)Ws[kc * 33 + o] * h_s[kc];
      }
      partials[tid] = acc;
      __syncthreads();
      if (tid < 32) {
        float g = 0.f;
#pragma unroll
        for (int q = 0; q < 8; ++q) g += partials[q * 32 + tid];
        gates_s[tid] = g;
      }
    } else {
      if (tid < 32) gates_s[tid] = 0.f;
    }
    __syncthreads();
    if (tid < 8) {
      const int j = tid;
      const long xb = (long)seq * 2048 + w * 8 + j;
      const float gi = gates_s[j] + bias_s[j] + xg[xb];
      const float gf = gates_s[8 + j] + bias_s[8 + j] + xg[xb + 512];
      const float gg = gates_s[16 + j] + bias_s[16 + j] + xg[xb + 1024];
      const float go = gates_s[24 + j] + bias_s[24 + j] + xg[xb + 1536];
      const float c = sigm(gf) * c_reg + sigm(gi) * tanh_(gg);
      c_reg = c;
      const float h = sigm(go) * tanh_(c);
      st_dev(&hsw[(dir * 2 + (s & 1)) * 512 + w * 8 + j],
             __builtin_bit_cast(unsigned int, h));
      outp[(long)seq * 1024 + dir * 512 + w * 8 + j] = h;
    }
    wg_barrier(fl, w, poll_idx, s + 1, tid, wave);
  }
}

// ---------------------------------------------------------------------------
__global__ __launch_bounds__(64) void final_linear(const float* __restrict__ hin,
                                                   const float* __restrict__ W,
                                                   const float* __restrict__ b,
                                                   float* __restrict__ out) {
  const int row = blockIdx.x, lane = threadIdx.x;
  float p[7] = {};
  for (int k = lane; k < 1024; k += 64) {
    const float hv = hin[row * 1024 + k];
#pragma unroll
    for (int oo = 0; oo < 7; ++oo) p[oo] += hv * W[oo * 1024 + k];
  }
#pragma unroll
  for (int oo = 0; oo < 7; ++oo)
#pragma unroll
    for (int off = 32; off; off >>= 1) p[oo] += __shfl_xor(p[oo], off);
  if (lane == 0)
#pragma unroll
    for (int oo = 0; oo < 7; ++oo) out[row * 7 + oo] = p[oo] + b[oo];
}

// ---------------------------------------------------------------------------
extern "C" void kernel_launch(void* const* d_in, const int* in_sizes, int n_in,
                              void* d_out, int out_size, void* d_ws,
                              size_t ws_size, hipStream_t stream) {
  const int* tokens = (const int*)d_in[0];
  const int* lengths = (const int*)d_in[1];
  const float* embed = (const float*)d_in[2];
  const float* tWih_f = (const float*)d_in[3];
  const float* tWhh_f = (const float*)d_in[4];
  const float* tbih_f = (const float*)d_in[5];
  const float* tbhh_f = (const float*)d_in[6];
  const float* tWih_b = (const float*)d_in[7];
  const float* tWhh_b = (const float*)d_in[8];
  const float* tbih_b = (const float*)d_in[9];
  const float* tbhh_b = (const float*)d_in[10];
  const float* attnW = (const float*)d_in[11];
  const float* attnB = (const float*)d_in[12];
  const float* attnCtx = (const float*)d_in[13];
  const float* sWih_f = (const float*)d_in[14];
  const float* sWhh_f = (const float*)d_in[15];
  const float* sbih_f = (const float*)d_in[16];
  const float* sbhh_f = (const float*)d_in[17];
  const float* sWih_b = (const float*)d_in[18];
  const float* sWhh_b = (const float*)d_in[19];
  const float* sbih_b = (const float*)d_in[20];
  const float* sbhh_b = (const float*)d_in[21];
  const float* linW = (const float*)d_in[22];
  const float* linB = (const float*)d_in[23];
  float* out = (float*)d_out;
  char* ws = (char*)d_ws;
  if (ws_size < TOTAL_WS) {
    sentinel_kernel<<<1, 256, 0, stream>>>(out, out_size);
    return;
  }

  f16* emb_h = (f16*)(ws + O_EMBH);
  f16* enc = (f16*)(ws + O_ENC);
  unsigned int* hbw = (unsigned int*)(ws + O_HBUF);
  float* aw = (float*)(ws + O_AW);
  float* ctxW = (float*)(ws + O_CTXW);
  float* cb = ctxW + 4096;
  f16* sent_h = (f16*)(ws + O_SENTH);
  float* xgs = (float*)(ws + O_XGS);
  unsigned int* hsw = (unsigned int*)(ws + O_HSBUF);
  float* out_sent = (float*)(ws + O_OUTS);
  int* flags = (int*)(ws + O_FLAGS);

  hipFuncSetAttribute((const void*)tok_lstm,
                      hipFuncAttributeMaxDynamicSharedMemorySize, TOK_LDS);

  hipMemsetAsync(ws + O_FLAGS, 0, 2048, stream);

  embed_kernel<<<8192, 256, 0, stream>>>(tokens, embed, emb_h);
  ctxw_kernel<<<4, 256, 0, stream>>>(attnW, attnB, attnCtx, ctxW, cb);

  tok_lstm<<<256, 512, TOK_LDS, stream>>>(
      emb_h, tWhh_f, tWhh_b, tWih_f, tWih_b, tbih_f, tbhh_f, tbih_b, tbhh_b,
      hbw, enc, flags);

  attn_scores<<<8192, 256, 0, stream>>>(enc, ctxW, cb, lengths, aw);
  attn_pool<<<256, 256, 0, stream>>>(enc, aw, sent_h);

  gemm_a16_b32<<<dim3(2, 16), 256, 0, stream>>>(
      sent_h, sWih_f, xgs, 256, 2048, 4096, 4096, 4096, 2048);
  gemm_a16_b32<<<dim3(2, 16), 256, 0, stream>>>(
      sent_h, sWih_b, xgs + 256 * 2048, 256, 2048, 4096, 4096, 4096, 2048);

  sent_lstm<<<128, 256, 0, stream>>>(xgs, sWhh_f, sWhh_b, sbih_f, sbhh_f,
                                     sbih_b, sbhh_b, hsw, out_sent, flags);

  final_linear<<<256, 64, 0, stream>>>(out_sent, linW, linB, out);
}